// Round 22
// baseline (94.560 us; speedup 1.0000x reference)
//
#include <hip/hip_runtime.h>
#include <hip/hip_bf16.h>
#include <math.h>
#include <stdint.h>

// Self-attention: B=4, S=4096, Din=1024, dk=dv=128, fp32 in/out.
//   wprep    : W f32 -> Wt bf16 fragment-major (wave B-frag load = 1KB contiguous)
//   proj     : FUSED Q,K,V; 64-row tiles, grid 256, BLOCK 512 (8 waves);
//              W fragments in REGISTERS; x via 16K LDS dbuf, 2-deep register
//              prefetch; raw lgkm-only barriers. Q pre-scaled. Epilogue: ALL
//              outputs (Q,K,V) re-laid out via LDS -> coalesced uint4 stores.
//   attn_part: R5-VERBATIM flash attention (32x32 mfma, swapped QK^T,
//              in-register softmax, K+V double-buffered, 1 barrier/tile, ns=4)
//   merge    : combines the ns partials (softmax-weighted) -> out

#define SM_SCALE2 0.1275310225216245f  // 128^-0.5 * log2(e)

using f32x4  = __attribute__((ext_vector_type(4))) float;
using f32x16 = __attribute__((ext_vector_type(16))) float;
using bf16x8 = __attribute__((ext_vector_type(8))) short;
using s16x4  = __attribute__((ext_vector_type(4))) short;

#define GLD16(gp, lp) __builtin_amdgcn_global_load_lds(                      \
    (const __attribute__((address_space(1))) void*)(gp),                     \
    (__attribute__((address_space(3))) void*)(lp), 16, 0, 0)

__device__ __forceinline__ short f2bf(float f) {
  union { __hip_bfloat16 h; short s; } u;
  u.h = __float2bfloat16(f);
  return u.s;
}

// wprep: fragment-major Wt. short idx =
//   (((mat*16+T)*2+kc)*8+cg)*512 + (g*16+l15)*8 + e
// where k = T*64 + kc*32 + g*8 + e, col = cg*16 + l15.
__global__ __launch_bounds__(256) void wprep_k(const float* __restrict__ Wq,
                                               const float* __restrict__ Wk,
                                               const float* __restrict__ Wv,
                                               short* __restrict__ Wt) {
  int tid = blockIdx.x * 256 + threadIdx.x;  // 0 .. 3*131072-1
  int mat = tid >> 17;
  int r   = tid & 131071;
  int k   = r >> 7;
  int col = r & 127;
  const float* W = (mat == 0) ? Wq : ((mat == 1) ? Wk : Wv);
  const int T = k >> 6, kc = (k >> 5) & 1, g = (k >> 3) & 3, e = k & 7;
  const int cg = col >> 4, l = col & 15;
  Wt[((((mat * 16 + T) * 2 + kc) * 8 + cg) << 9) + ((g * 16 + l) << 3) + e] =
      f2bf(W[k * 128 + col]);
}

// proj: grid 256, block 512 (8 waves). Tile 64 rows x (3 mats x 128 cols), K-step 64.
// Wave w owns col-fragments f = 3w..3w+2 (f = m*8+cg). LDS 18K: xs dbuf 2x8K.
__global__ __launch_bounds__(512) void proj_k(const float* __restrict__ x,
                                              const short* __restrict__ Wt,
                                              const float* __restrict__ bq,
                                              const float* __restrict__ bk,
                                              const float* __restrict__ bv,
                                              short* __restrict__ Qb,
                                              short* __restrict__ Kb,
                                              short* __restrict__ Vt) {
  const int r0  = blockIdx.x * 64;
  const int tid  = threadIdx.x;
  const int lane = tid & 63;
  const int w    = tid >> 6;     // 0..7
  const int g    = lane >> 4;
  const int l15  = lane & 15;

  __shared__ __align__(16) char smem[18432];
  const char* Wtb = (const char*)Wt;

  f32x4 acc[3][4];   // [owned fragment fi][row block]
  #pragma unroll
  for (int fi = 0; fi < 3; ++fi)
    #pragma unroll
    for (int rb = 0; rb < 4; ++rb) acc[fi][rb] = (f32x4){0.f, 0.f, 0.f, 0.f};

  const int xrow = tid >> 3;   // 0..63
  const int xsl  = tid & 7;    // slot base; s = xsl + 8p covers 0..15

#define XS(B) (smem + (B) * 8192)

  // raw tile barrier: drain LDS ops only; register global loads stay in flight
#define BARX do {                                                             \
    __builtin_amdgcn_sched_barrier(0);                                        \
    asm volatile("s_waitcnt lgkmcnt(0)" ::: "memory");                        \
    __builtin_amdgcn_s_barrier();                                             \
    __builtin_amdgcn_sched_barrier(0);                                        \
  } while (0)

  // W fragments for this wave: 6 = [fi][kc]; wave-coalesced 1KB load per frag.
#define LOADW(DST, T) do {                                                    \
    _Pragma("unroll")                                                         \
    for (int i = 0; i < 6; ++i) {                                             \
      const int fi_ = i >> 1, kc_ = i & 1;                                    \
      const int f_  = w * 3 + fi_;                                            \
      const int m_  = f_ >> 3, cg_ = f_ & 7;                                  \
      DST[i] = *(const bf16x8*)(Wtb +                                         \
          ((((((m_ * 16 + (T)) * 2 + kc_) * 8) + cg_) << 10) +                \
           (lane << 4)));                                                     \
    }                                                                         \
  } while (0)

#define LOADX(FX, T) do {                                                     \
    _Pragma("unroll")                                                         \
    for (int p = 0; p < 2; ++p) {                                             \
      const int s = xsl + 8 * p;                                              \
      FX[p] = *(const float4*)(x + (size_t)(r0 + xrow) * 1024 + (T) * 64 + s * 4); \
    }                                                                         \
  } while (0)

#define WRITEX(B, FX) do {                                                    \
    char* xb_ = XS(B);                                                        \
    _Pragma("unroll")                                                         \
    for (int p = 0; p < 2; ++p) {                                             \
      const int s = xsl + 8 * p;                                              \
      s16x4 h = { f2bf(FX[p].x), f2bf(FX[p].y), f2bf(FX[p].z), f2bf(FX[p].w) }; \
      *(s16x4*)(xb_ + xrow * 128 + (((s >> 1) ^ (xrow & 7)) << 4) +           \
                ((s & 1) << 3)) = h;                                          \
    }                                                                         \
  } while (0)

#define COMP(B, WF) do {                                                      \
    const char* xb = XS(B);                                                   \
    _Pragma("unroll")                                                         \
    for (int kc = 0; kc < 2; ++kc) {                                          \
      bf16x8 a[4];                                                            \
      _Pragma("unroll")                                                       \
      for (int rb = 0; rb < 4; ++rb)                                          \
        a[rb] = *(const bf16x8*)(xb + (rb * 16 + l15) * 128 +                 \
                                 ((((kc << 2) + g) ^ (l15 & 7)) << 4));       \
      _Pragma("unroll")                                                       \
      for (int fi = 0; fi < 3; ++fi)                                          \
        _Pragma("unroll")                                                     \
        for (int rb = 0; rb < 4; ++rb)                                        \
          acc[fi][rb] = __builtin_amdgcn_mfma_f32_16x16x32_bf16(              \
              a[rb], WF[fi * 2 + kc], acc[fi][rb], 0, 0, 0);                  \
    }                                                                         \
  } while (0)

  bf16x8 wf[6];
  float4 fxA[2], fxB[2];

  // prologue: x(0)->xs0, W(0)->wf, x(1)->fxA (flies across barrier)
  {
    float4 fx0[2];
    LOADX(fx0, 0);
    WRITEX(0, fx0);
    LOADW(wf, 0);
    LOADX(fxA, 1);
  }
  BARX;

  #pragma unroll 1
  for (int t = 0; t < 16; t += 2) {
    // tile t (even): x in XS(0), W in wf
    if (t + 2 < 16) LOADX(fxB, t + 2);
    COMP(0, wf);
    LOADW(wf, t + 1);            // reload after last use; covered by WRITEX+bar
    WRITEX(1, fxA);              // fxA = x(t+1), loaded ~2 tiles ago
    BARX;
    // tile t+1 (odd): x in XS(1), W in wf
    if (t + 3 < 16) LOADX(fxA, t + 3);
    COMP(1, wf);
    if (t + 2 < 16) {
      LOADW(wf, t + 2);
      WRITEX(0, fxB);            // fxB = x(t+2)
    }
    BARX;
  }
#undef LOADW
#undef LOADX
#undef WRITEX
#undef COMP
#undef BARX
#undef XS

  // ---- epilogue: Q and K via LDS row-major re-layout -> coalesced stores ----
  // tb: [64 rows][132 shorts] (264B padded rows) = 16896 B
  {
    short* tb = (short*)smem;
    #pragma unroll
    for (int m_ = 0; m_ < 2; ++m_) {
      __syncthreads();   // tb free (main loop done / previous mat consumed)
      #pragma unroll
      for (int fi = 0; fi < 3; ++fi) {
        const int f = w * 3 + fi;
        if ((f >> 3) == m_) {                  // wave-uniform
          const int col = (f & 7) * 16 + l15;
          const float bc = ((m_ == 0) ? bq : bk)[col];
          #pragma unroll
          for (int rb = 0; rb < 4; ++rb)
            #pragma unroll
            for (int r = 0; r < 4; ++r) {
              float v = acc[fi][rb][r] + bc;
              if (m_ == 0) v *= SM_SCALE2;
              tb[(rb * 16 + (g << 2) + r) * 132 + col] = f2bf(v);
            }
        }
      }
      __syncthreads();
      short* dst = (m_ == 0) ? Qb : Kb;
      const int qr = tid >> 3;   // 0..63
      const int qc = tid & 7;    // 8 threads x 32B cover one 256B row
      #pragma unroll
      for (int j = 0; j < 2; ++j) {
        uint4 vd = *(const uint4*)((char*)tb + qr * 264 + qc * 32 + j * 16);
        *(uint4*)((char*)dst +
                  (((size_t)(r0 + qr) * 128 + qc * 16 + j * 8) * 2)) = vd;
      }
    }
  }
  // V: transpose via LDS (col-major tb, coalesced stores to Vt[b][d][s])
  __syncthreads();
  {
    short* tb = (short*)smem;  // [128][72] bf16 (144B rows, padded)
    #pragma unroll
    for (int fi = 0; fi < 3; ++fi) {
      const int f = w * 3 + fi;
      if ((f >> 3) == 2) {
        const int col = (f & 7) * 16 + l15;
        const float bc = bv[col];
        #pragma unroll
        for (int rb = 0; rb < 4; ++rb)
          #pragma unroll
          for (int r = 0; r < 4; ++r)
            tb[col * 72 + rb * 16 + (g << 2) + r] = f2bf(acc[fi][rb][r] + bc);
      }
    }
    __syncthreads();
    const int bb = r0 >> 12;
    const int s0 = r0 & 4095;
    const int d  = tid >> 2;   // 0..127
    #pragma unroll
    for (int j = 0; j < 2; ++j) {
      uint4 vd = *(const uint4*)((char*)tb + d * 144 + (tid & 3) * 32 + j * 16);
      *(uint4*)((char*)Vt +
                ((size_t)(bb * 128 + d) * 4096 + s0 + (tid & 3) * 16 + j * 8) * 2) = vd;
    }
  }
}

// attn_part (R5 VERBATIM): grid 128*ns (XCD-swizzled), block 256 = 4 waves x 32 q.
// 64K LDS: per buffer {K 16K [64][256B] + V 16K [128][128B]}, single barrier/tile.
__global__ __launch_bounds__(256, 2) void attn_part_k(
    const short* __restrict__ Qb, const short* __restrict__ Kb,
    const short* __restrict__ Vt, float* __restrict__ part,
    float2* __restrict__ ml, float* __restrict__ out, int ns, int direct) {
  const int nwg  = gridDim.x;
  const int bid  = blockIdx.x;
  const int orig = (bid & 7) * (nwg >> 3) + (bid >> 3);
  const int split = orig >> 7;       // 0..ns-1
  const int qb    = orig & 127;      // q-block of 128 rows
  const int nkt   = 64 / ns;
  const int kt0   = split * nkt;

  const int tid  = threadIdx.x;
  const int lane = tid & 63;
  const int w    = tid >> 6;
  const int l31  = lane & 31;
  const bool hi  = lane >= 32;

  __shared__ __align__(16) char smem[65536];  // 2 x (Kt 16K + Vts 16K)

  const int bb = qb >> 5;                             // batch
  const size_t qg = (size_t)qb * 128 + w * 32 + l31;  // global q-row

  const char* Kg = (const char*)(Kb + ((size_t)bb << 19));
  const char* Vg = (const char*)(Vt + ((size_t)bb << 19));

  // Q row in registers (pre-scaled by SM_SCALE2 in proj)
  bf16x8 qf[8];
  {
    const short* qp = Qb + qg * 128;
    #pragma unroll
    for (int kd = 0; kd < 8; ++kd)
      qf[kd] = *(const bf16x8*)(qp + 16 * kd + (hi ? 8 : 0));
  }

  float m = -__builtin_inff(), lsum = 0.f;
  f32x16 oacc[4];
  #pragma unroll
  for (int dt = 0; dt < 4; ++dt) oacc[dt] = (f32x16)(0.0f);

#define STAGE(BUF, KT) do {                                                   \
    char* kb_ = smem + (BUF) * 32768;                                         \
    char* vb_ = kb_ + 16384;                                                  \
    _Pragma("unroll")                                                         \
    for (int c = 0; c < 4; ++c) {                                             \
      const int o   = w * 4096 + c * 1024 + lane * 16;                        \
      const int kr  = o >> 8;                                                 \
      const int kc_ = (o >> 4) & 15;                                          \
      GLD16(Kg + (size_t)((KT) * 64 + kr) * 256 + ((kc_ ^ (kr & 15)) << 4),   \
            kb_ + w * 4096 + c * 1024);                                       \
      const int dr  = o >> 7;                                                 \
      const int dc_ = (o >> 4) & 7;                                           \
      GLD16(Vg + (size_t)dr * 8192 + (size_t)(KT) * 128 + ((dc_ ^ (dr & 7)) << 4), \
            vb_ + w * 4096 + c * 1024);                                       \
    }                                                                         \
  } while (0)

  STAGE(0, kt0);
  __syncthreads();

  for (int t = 0; t < nkt; ++t) {
    const int cur = t & 1;
    if (t + 1 < nkt) STAGE(cur ^ 1, kt0 + t + 1);  // prefetch, lands during this tile

    const char* KT_ = smem + cur * 32768;
    const char* VT_ = KT_ + 16384;

    // ---- S^T = K · Q^T : lane holds S[k = 32*kt2 + crow(reg,hi)][q = l31] ----
    f32x16 s0 = (f32x16)(0.0f), s1 = (f32x16)(0.0f);
    __builtin_amdgcn_s_setprio(1);
    #pragma unroll
    for (int kd = 0; kd < 8; ++kd) {
      const int ch = (((2 * kd + (hi ? 1 : 0)) ^ (l31 & 15)) << 4);
      bf16x8 k0 = *(const bf16x8*)(KT_ + l31 * 256 + ch);
      bf16x8 k1 = *(const bf16x8*)(KT_ + (32 + l31) * 256 + ch);
      s0 = __builtin_amdgcn_mfma_f32_32x32x16_bf16(k0, qf[kd], s0, 0, 0, 0);
      s1 = __builtin_amdgcn_mfma_f32_32x32x16_bf16(k1, qf[kd], s1, 0, 0, 0);
    }
    __builtin_amdgcn_s_setprio(0);

    // ---- online softmax (scores already in log2 domain) ----
    float mx = s0[0];
    #pragma unroll
    for (int i = 1; i < 16; ++i) mx = fmaxf(mx, s0[i]);
    #pragma unroll
    for (int i = 0; i < 16; ++i) mx = fmaxf(mx, s1[i]);
    mx = fmaxf(mx, __shfl_xor(mx, 32));
    if (!__all(mx - m <= 8.f)) {        // defer-max (T13)
      const float mn = fmaxf(m, mx);
      const float al = exp2f(m - mn);
      m = mn;
      lsum *= al;
      #pragma unroll
      for (int dt = 0; dt < 4; ++dt)
        #pragma unroll
        for (int i = 0; i < 16; ++i) oacc[dt][i] *= al;
    }
    float rs = 0.f;
    #pragma unroll
    for (int i = 0; i < 16; ++i) { s0[i] = exp2f(s0[i] - m); rs += s0[i]; }
    #pragma unroll
    for (int i = 0; i < 16; ++i) { s1[i] = exp2f(s1[i] - m); rs += s1[i]; }
    rs += __shfl_xor(rs, 32);
    lsum += rs;

    // ---- P -> bf16 words: W[kt2][rho][rh] covers k = 32*kt2 + 8*rho + 4*hi + 2*rh ----
    unsigned int W[2][4][2];
    #pragma unroll
    for (int rho = 0; rho < 4; ++rho)
      #pragma unroll
      for (int rh = 0; rh < 2; ++rh) {
        asm("v_cvt_pk_bf16_f32 %0, %1, %2"
            : "=v"(W[0][rho][rh]) : "v"(s0[4 * rho + 2 * rh]), "v"(s0[4 * rho + 2 * rh + 1]));
        asm("v_cvt_pk_bf16_f32 %0, %1, %2"
            : "=v"(W[1][rho][rh]) : "v"(s1[4 * rho + 2 * rh]), "v"(s1[4 * rho + 2 * rh + 1]));
      }

    // ---- O^T += V^T · P^T : one xor32 exchange per fragment pair ----
    #pragma unroll
    for (int ks = 0; ks < 4; ++ks) {
      const int t2 = ks >> 1, ksl = ks & 1;
      const unsigned int wl0 = W[t2][2 * ksl][0],     wl1 = W[t2][2 * ksl][1];
      const unsigned int wh0 = W[t2][2 * ksl + 1][0], wh1 = W[t2][2 * ksl + 1][1];
      const unsigned int r0 = __shfl_xor(hi ? wl0 : wh0, 32);
      const unsigned int r1 = __shfl_xor(hi ? wl1 : wh1, 32);
      union { unsigned int u[4]; bf16x8 v; } pb;
      pb.u[0] = hi ? r0 : wl0;
      pb.u[1] = hi ? r1 : wl1;
      pb.u[2] = hi ? wh0 : r0;
      pb.u[3] = hi ? wh1 : r1;
      __builtin_amdgcn_s_setprio(1);
      #pragma unroll
      for (int dt = 0; dt < 4; ++dt) {
        const int row = 32 * dt + l31;
        bf16x8 vf = *(const bf16x8*)(VT_ + row * 128 +
                                     (((2 * ks + (hi ? 1 : 0)) ^ (row & 7)) << 4));
        oacc[dt] = __builtin_amdgcn_mfma_f32_32x32x16_bf16(vf, pb.v, oacc[dt], 0, 0, 0);
      }
      __builtin_amdgcn_s_setprio(0);
    }

    __syncthreads();  // drains exactly the staging the next tile needs
  }
#undef STAGE

  // ---- epilogue: lane holds O^T[d = 32*dt + crow(reg,hi)][q = l31] ----
  const float sc = direct ? (1.f / lsum) : 1.f;
  float* dst = direct ? (out + qg * 128)
                      : (part + ((size_t)split * 16384 + qg) * 128);
  #pragma unroll
  for (int dt = 0; dt < 4; ++dt)
    #pragma unroll
    for (int rq = 0; rq < 4; ++rq) {
      f32x4 v = { oacc[dt][4 * rq + 0] * sc, oacc[dt][4 * rq + 1] * sc,
                  oacc[dt][4 * rq + 2] * sc, oacc[dt][4 * rq + 3] * sc };
      *(f32x4*)(dst + dt * 32 + rq * 8 + (hi ? 4 : 0)) = v;
    }
  if (!direct && lane < 32)
    ml[(size_t)split * 16384 + qg] = make_float2(m, lsum);
}

// merge: combine ns softmax partials. grid 2048 x 256, one float4 per thread.
__global__ __launch_bounds__(256) void merge_k(const float* __restrict__ part,
                                               const float2* __restrict__ ml,
                                               float* __restrict__ out, int ns) {
  const int idx = blockIdx.x * 256 + threadIdx.x;  // 0 .. 16384*32-1
  const int row = idx >> 5;
  const int c4  = idx & 31;

  float M = -__builtin_inff();
  for (int s = 0; s < ns; ++s) M = fmaxf(M, ml[s * 16384 + row].x);
  float L = 0.f;
  for (int s = 0; s < ns; ++s) {
    const float2 v = ml[s * 16384 + row];
    L += v.y * exp2f(v.x - M);
  }
  const float invL = 1.f / L;

  f32x4 o = (f32x4){0.f, 0.f, 0.f, 0.f};
  for (int s = 0; s < ns; ++s) {
    const float wgt = exp2f(ml[s * 16384 + row].x - M) * invL;
    const f32x4 a = *(const f32x4*)(part + ((size_t)s * 16384 + row) * 128 + c4 * 4);
    o += a * wgt;
  }
  *(f32x4*)(out + (size_t)row * 128 + c4 * 4) = o;
}

extern "C" void kernel_launch(void* const* d_in, const int* in_sizes, int n_in,
                              void* d_out, int out_size, void* d_ws, size_t ws_size,
                              hipStream_t stream) {
  (void)in_sizes; (void)n_in; (void)out_size;
  const float* x  = (const float*)d_in[0];
  const float* Wq = (const float*)d_in[1];
  const float* bq = (const float*)d_in[2];
  const float* Wk = (const float*)d_in[3];
  const float* bk = (const float*)d_in[4];
  const float* Wv = (const float*)d_in[5];
  const float* bv = (const float*)d_in[6];
  float* out = (float*)d_out;

  // workspace layout
  char* ws = (char*)d_ws;
  short* Wt = (short*)ws;                           // 786432 B  : Wt bf16 fragment-major
  short* Qb = (short*)(ws + 786432);                // 4 MiB     : Q bf16 [16384][128]
  short* Kb = (short*)(ws + 786432 + 4194304);      // 4 MiB     : K bf16 [16384][128]
  short* Vt = (short*)(ws + 786432 + 2 * 4194304);  // 4 MiB     : V^T bf16 [4][128][4096]
  const size_t base = 786432 + 3ull * 4194304;      // 13,369,344

  const size_t per_split = 16384ull * 128 * 4 + 16384ull * 8;
  int ns = 0;
  if (ws_size >= base + 4 * per_split)      ns = 4;
  else if (ws_size >= base + 2 * per_split) ns = 2;
  const int direct = (ns == 0);
  if (direct) ns = 1;

  float*  part = (float*)(ws + base);
  float2* mlp  = (float2*)(ws + base + (size_t)ns * 16384ull * 128 * 4);

  wprep_k<<<dim3(1536), dim3(256), 0, stream>>>(Wq, Wk, Wv, Wt);
  proj_k<<<dim3(256), dim3(512), 0, stream>>>(x, Wt, bq, bk, bv, Qb, Kb, Vt);
  attn_part_k<<<dim3(128 * ns), dim3(256), 0, stream>>>(Qb, Kb, Vt, part, mlp, out,
                                                        ns, direct);
  if (!direct)
    merge_k<<<dim3(2048), dim3(256), 0, stream>>>(part, mlp, out, ns);
}

// Round 23
// 92.135 us; speedup vs baseline: 1.0263x; 1.0263x over previous
//
#include <hip/hip_runtime.h>
#include <hip/hip_bf16.h>
#include <math.h>
#include <stdint.h>

// Self-attention: B=4, S=4096, Din=1024, dk=dv=128, fp32 in/out.
//   wprep    : W f32 -> Wt bf16 fragment-major (wave B-frag load = 1KB contiguous)
//   proj     : R21-verbatim FUSED Q,K,V; 64-row tiles, grid 256, block 512;
//              W fragments in REGISTERS; x via 16K LDS dbuf, 2-deep prefetch;
//              raw lgkm-only barriers. Q pre-scaled by 128^-0.5*log2(e).
//   attn_part: R5 flash attention core with T12 permlane32_swap replacing all
//              lane^32 ds_bpermute exchanges (softmax reduce + PV P-exchange).
//   merge    : combines the ns partials (softmax-weighted) -> out

#define SM_SCALE2 0.1275310225216245f  // 128^-0.5 * log2(e)

using f32x4  = __attribute__((ext_vector_type(4))) float;
using f32x16 = __attribute__((ext_vector_type(16))) float;
using bf16x8 = __attribute__((ext_vector_type(8))) short;
using s16x4  = __attribute__((ext_vector_type(4))) short;
using u32x2  = __attribute__((ext_vector_type(2))) unsigned int;

#define GLD16(gp, lp) __builtin_amdgcn_global_load_lds(                      \
    (const __attribute__((address_space(1))) void*)(gp),                     \
    (__attribute__((address_space(3))) void*)(lp), 16, 0, 0)

__device__ __forceinline__ short f2bf(float f) {
  union { __hip_bfloat16 h; short s; } u;
  u.h = __float2bfloat16(f);
  return u.s;
}

// wprep: fragment-major Wt. short idx =
//   (((mat*16+T)*2+kc)*8+cg)*512 + (g*16+l15)*8 + e
__global__ __launch_bounds__(256) void wprep_k(const float* __restrict__ Wq,
                                               const float* __restrict__ Wk,
                                               const float* __restrict__ Wv,
                                               short* __restrict__ Wt) {
  int tid = blockIdx.x * 256 + threadIdx.x;  // 0 .. 3*131072-1
  int mat = tid >> 17;
  int r   = tid & 131071;
  int k   = r >> 7;
  int col = r & 127;
  const float* W = (mat == 0) ? Wq : ((mat == 1) ? Wk : Wv);
  const int T = k >> 6, kc = (k >> 5) & 1, g = (k >> 3) & 3, e = k & 7;
  const int cg = col >> 4, l = col & 15;
  Wt[((((mat * 16 + T) * 2 + kc) * 8 + cg) << 9) + ((g * 16 + l) << 3) + e] =
      f2bf(W[k * 128 + col]);
}

// proj (R21-verbatim): grid 256, block 512 (8 waves). 64 rows x (3x128 cols), K-step 64.
__global__ __launch_bounds__(512) void proj_k(const float* __restrict__ x,
                                              const short* __restrict__ Wt,
                                              const float* __restrict__ bq,
                                              const float* __restrict__ bk,
                                              const float* __restrict__ bv,
                                              short* __restrict__ Qb,
                                              short* __restrict__ Kb,
                                              short* __restrict__ Vt) {
  const int r0  = blockIdx.x * 64;
  const int tid  = threadIdx.x;
  const int lane = tid & 63;
  const int w    = tid >> 6;     // 0..7
  const int g    = lane >> 4;
  const int l15  = lane & 15;

  __shared__ __align__(16) char smem[18432];
  const char* Wtb = (const char*)Wt;

  f32x4 acc[3][4];   // [owned fragment fi][row block]
  #pragma unroll
  for (int fi = 0; fi < 3; ++fi)
    #pragma unroll
    for (int rb = 0; rb < 4; ++rb) acc[fi][rb] = (f32x4){0.f, 0.f, 0.f, 0.f};

  const int xrow = tid >> 3;   // 0..63
  const int xsl  = tid & 7;    // slot base; s = xsl + 8p covers 0..15

#define XS(B) (smem + (B) * 8192)

#define BARX do {                                                             \
    __builtin_amdgcn_sched_barrier(0);                                        \
    asm volatile("s_waitcnt lgkmcnt(0)" ::: "memory");                        \
    __builtin_amdgcn_s_barrier();                                             \
    __builtin_amdgcn_sched_barrier(0);                                        \
  } while (0)

#define LOADW(DST, T) do {                                                    \
    _Pragma("unroll")                                                         \
    for (int i = 0; i < 6; ++i) {                                             \
      const int fi_ = i >> 1, kc_ = i & 1;                                    \
      const int f_  = w * 3 + fi_;                                            \
      const int m_  = f_ >> 3, cg_ = f_ & 7;                                  \
      DST[i] = *(const bf16x8*)(Wtb +                                         \
          ((((((m_ * 16 + (T)) * 2 + kc_) * 8) + cg_) << 10) +                \
           (lane << 4)));                                                     \
    }                                                                         \
  } while (0)

#define LOADX(FX, T) do {                                                     \
    _Pragma("unroll")                                                         \
    for (int p = 0; p < 2; ++p) {                                             \
      const int s = xsl + 8 * p;                                              \
      FX[p] = *(const float4*)(x + (size_t)(r0 + xrow) * 1024 + (T) * 64 + s * 4); \
    }                                                                         \
  } while (0)

#define WRITEX(B, FX) do {                                                    \
    char* xb_ = XS(B);                                                        \
    _Pragma("unroll")                                                         \
    for (int p = 0; p < 2; ++p) {                                             \
      const int s = xsl + 8 * p;                                              \
      s16x4 h = { f2bf(FX[p].x), f2bf(FX[p].y), f2bf(FX[p].z), f2bf(FX[p].w) }; \
      *(s16x4*)(xb_ + xrow * 128 + (((s >> 1) ^ (xrow & 7)) << 4) +           \
                ((s & 1) << 3)) = h;                                          \
    }                                                                         \
  } while (0)

#define COMP(B, WF) do {                                                      \
    const char* xb = XS(B);                                                   \
    _Pragma("unroll")                                                         \
    for (int kc = 0; kc < 2; ++kc) {                                          \
      bf16x8 a[4];                                                            \
      _Pragma("unroll")                                                       \
      for (int rb = 0; rb < 4; ++rb)                                          \
        a[rb] = *(const bf16x8*)(xb + (rb * 16 + l15) * 128 +                 \
                                 ((((kc << 2) + g) ^ (l15 & 7)) << 4));       \
      _Pragma("unroll")                                                       \
      for (int fi = 0; fi < 3; ++fi)                                          \
        _Pragma("unroll")                                                     \
        for (int rb = 0; rb < 4; ++rb)                                        \
          acc[fi][rb] = __builtin_amdgcn_mfma_f32_16x16x32_bf16(              \
              a[rb], WF[fi * 2 + kc], acc[fi][rb], 0, 0, 0);                  \
    }                                                                         \
  } while (0)

  bf16x8 wf[6];
  float4 fxA[2], fxB[2];

  {
    float4 fx0[2];
    LOADX(fx0, 0);
    WRITEX(0, fx0);
    LOADW(wf, 0);
    LOADX(fxA, 1);
  }
  BARX;

  #pragma unroll 1
  for (int t = 0; t < 16; t += 2) {
    if (t + 2 < 16) LOADX(fxB, t + 2);
    COMP(0, wf);
    LOADW(wf, t + 1);
    WRITEX(1, fxA);
    BARX;
    if (t + 3 < 16) LOADX(fxA, t + 3);
    COMP(1, wf);
    if (t + 2 < 16) {
      LOADW(wf, t + 2);
      WRITEX(0, fxB);
    }
    BARX;
  }
#undef LOADW
#undef LOADX
#undef WRITEX
#undef COMP
#undef BARX
#undef XS

  // epilogue: per owned fragment. Q (pre-scaled) / K direct stores.
  #pragma unroll
  for (int fi = 0; fi < 3; ++fi) {
    const int f   = w * 3 + fi;
    const int m_  = f >> 3;
    const int cg_ = f & 7;
    const int col = cg_ * 16 + l15;
    if (m_ < 2) {
      short* dst = (m_ == 0) ? Qb : Kb;
      const float bc = ((m_ == 0) ? bq : bk)[col];
      #pragma unroll
      for (int rb = 0; rb < 4; ++rb)
        #pragma unroll
        for (int r = 0; r < 4; ++r) {
          float v = acc[fi][rb][r] + bc;
          if (m_ == 0) v *= SM_SCALE2;
          dst[(size_t)(r0 + rb * 16 + (g << 2) + r) * 128 + col] = f2bf(v);
        }
    }
  }
  // V: transpose via LDS
  __syncthreads();
  {
    short* tb = (short*)smem;  // [128][72] bf16 (144B rows, padded)
    #pragma unroll
    for (int fi = 0; fi < 3; ++fi) {
      const int f = w * 3 + fi;
      if ((f >> 3) == 2) {
        const int col = (f & 7) * 16 + l15;
        const float bc = bv[col];
        #pragma unroll
        for (int rb = 0; rb < 4; ++rb)
          #pragma unroll
          for (int r = 0; r < 4; ++r)
            tb[col * 72 + rb * 16 + (g << 2) + r] = f2bf(acc[fi][rb][r] + bc);
      }
    }
    __syncthreads();
    const int bb = r0 >> 12;
    const int s0 = r0 & 4095;
    const int d  = tid >> 2;   // 0..127
    #pragma unroll
    for (int j = 0; j < 2; ++j) {
      uint4 vd = *(const uint4*)((char*)tb + d * 144 + (tid & 3) * 32 + j * 16);
      *(uint4*)((char*)Vt +
                ((size_t)(bb * 128 + d) * 4096 + s0 + (tid & 3) * 16 + j * 8) * 2) = vd;
    }
  }
}

// attn_part (R5 core + permlane32_swap exchanges): grid 128*ns, 4 waves x 32 q.
__global__ __launch_bounds__(256, 2) void attn_part_k(
    const short* __restrict__ Qb, const short* __restrict__ Kb,
    const short* __restrict__ Vt, float* __restrict__ part,
    float2* __restrict__ ml, float* __restrict__ out, int ns, int direct) {
  const int nwg  = gridDim.x;
  const int bid  = blockIdx.x;
  const int orig = (bid & 7) * (nwg >> 3) + (bid >> 3);
  const int split = orig >> 7;       // 0..ns-1
  const int qb    = orig & 127;      // q-block of 128 rows
  const int nkt   = 64 / ns;
  const int kt0   = split * nkt;

  const int tid  = threadIdx.x;
  const int lane = tid & 63;
  const int w    = tid >> 6;
  const int l31  = lane & 31;
  const bool hi  = lane >= 32;

  __shared__ __align__(16) char smem[65536];  // 2 x (Kt 16K + Vts 16K)

  const int bb = qb >> 5;                             // batch
  const size_t qg = (size_t)qb * 128 + w * 32 + l31;  // global q-row

  const char* Kg = (const char*)(Kb + ((size_t)bb << 19));
  const char* Vg = (const char*)(Vt + ((size_t)bb << 19));

  // Q row in registers (pre-scaled by SM_SCALE2 in proj)
  bf16x8 qf[8];
  {
    const short* qp = Qb + qg * 128;
    #pragma unroll
    for (int kd = 0; kd < 8; ++kd)
      qf[kd] = *(const bf16x8*)(qp + 16 * kd + (hi ? 8 : 0));
  }

  float m = -__builtin_inff(), lsum = 0.f;
  f32x16 oacc[4];
  #pragma unroll
  for (int dt = 0; dt < 4; ++dt) oacc[dt] = (f32x16)(0.0f);

#define STAGE(BUF, KT) do {                                                   \
    char* kb_ = smem + (BUF) * 32768;                                         \
    char* vb_ = kb_ + 16384;                                                  \
    _Pragma("unroll")                                                         \
    for (int c = 0; c < 4; ++c) {                                             \
      const int o   = w * 4096 + c * 1024 + lane * 16;                        \
      const int kr  = o >> 8;                                                 \
      const int kc_ = (o >> 4) & 15;                                          \
      GLD16(Kg + (size_t)((KT) * 64 + kr) * 256 + ((kc_ ^ (kr & 15)) << 4),   \
            kb_ + w * 4096 + c * 1024);                                       \
      const int dr  = o >> 7;                                                 \
      const int dc_ = (o >> 4) & 7;                                           \
      GLD16(Vg + (size_t)dr * 8192 + (size_t)(KT) * 128 + ((dc_ ^ (dr & 7)) << 4), \
            vb_ + w * 4096 + c * 1024);                                       \
    }                                                                         \
  } while (0)

  STAGE(0, kt0);
  __syncthreads();

  for (int t = 0; t < nkt; ++t) {
    const int cur = t & 1;
    if (t + 1 < nkt) STAGE(cur ^ 1, kt0 + t + 1);  // prefetch, lands during this tile

    const char* KT_ = smem + cur * 32768;
    const char* VT_ = KT_ + 16384;

    // ---- S^T = K · Q^T : lane holds S[k = 32*kt2 + crow(reg,hi)][q = l31] ----
    f32x16 s0 = (f32x16)(0.0f), s1 = (f32x16)(0.0f);
    __builtin_amdgcn_s_setprio(1);
    #pragma unroll
    for (int kd = 0; kd < 8; ++kd) {
      const int ch = (((2 * kd + (hi ? 1 : 0)) ^ (l31 & 15)) << 4);
      bf16x8 k0 = *(const bf16x8*)(KT_ + l31 * 256 + ch);
      bf16x8 k1 = *(const bf16x8*)(KT_ + (32 + l31) * 256 + ch);
      s0 = __builtin_amdgcn_mfma_f32_32x32x16_bf16(k0, qf[kd], s0, 0, 0, 0);
      s1 = __builtin_amdgcn_mfma_f32_32x32x16_bf16(k1, qf[kd], s1, 0, 0, 0);
    }
    __builtin_amdgcn_s_setprio(0);

    // ---- online softmax; lane^32 reduce via permlane32_swap (VALU pipe) ----
    float mx = s0[0];
    #pragma unroll
    for (int i = 1; i < 16; ++i) mx = fmaxf(mx, s0[i]);
    #pragma unroll
    for (int i = 0; i < 16; ++i) mx = fmaxf(mx, s1[i]);
    {
      union { float f; unsigned u; } mi; mi.f = mx;
      u32x2 mp = __builtin_amdgcn_permlane32_swap(mi.u, mi.u, false, false);
      union { unsigned u; float f; } a0, a1; a0.u = mp[0]; a1.u = mp[1];
      mx = fmaxf(a0.f, a1.f);
    }
    if (!__all(mx - m <= 8.f)) {        // defer-max (T13)
      const float mn = fmaxf(m, mx);
      const float al = exp2f(m - mn);
      m = mn;
      lsum *= al;
      #pragma unroll
      for (int dt = 0; dt < 4; ++dt)
        #pragma unroll
        for (int i = 0; i < 16; ++i) oacc[dt][i] *= al;
    }
    float rs = 0.f;
    #pragma unroll
    for (int i = 0; i < 16; ++i) { s0[i] = exp2f(s0[i] - m); rs += s0[i]; }
    #pragma unroll
    for (int i = 0; i < 16; ++i) { s1[i] = exp2f(s1[i] - m); rs += s1[i]; }
    {
      union { float f; unsigned u; } ri; ri.f = rs;
      u32x2 rp = __builtin_amdgcn_permlane32_swap(ri.u, ri.u, false, false);
      union { unsigned u; float f; } a0, a1; a0.u = rp[0]; a1.u = rp[1];
      rs = a0.f + a1.f;
    }
    lsum += rs;

    // ---- P -> bf16 words: W[kt2][rho][rh] covers k = 32*kt2 + 8*rho + 4*hi + 2*rh ----
    unsigned int W[2][4][2];
    #pragma unroll
    for (int rho = 0; rho < 4; ++rho)
      #pragma unroll
      for (int rh = 0; rh < 2; ++rh) {
        asm("v_cvt_pk_bf16_f32 %0, %1, %2"
            : "=v"(W[0][rho][rh]) : "v"(s0[4 * rho + 2 * rh]), "v"(s0[4 * rho + 2 * rh + 1]));
        asm("v_cvt_pk_bf16_f32 %0, %1, %2"
            : "=v"(W[1][rho][rh]) : "v"(s1[4 * rho + 2 * rh]), "v"(s1[4 * rho + 2 * rh + 1]));
      }

    // ---- O^T += V^T · P^T : P exchange via permlane32_swap (was 2 bpermute
    //      + 4 cndmask per ks; now 2 permlane, outputs are exactly u[0]/u[2]) ----
    #pragma unroll
    for (int ks = 0; ks < 4; ++ks) {
      const int t2 = ks >> 1, ksl = ks & 1;
      const unsigned int wl0 = W[t2][2 * ksl][0],     wl1 = W[t2][2 * ksl][1];
      const unsigned int wh0 = W[t2][2 * ksl + 1][0], wh1 = W[t2][2 * ksl + 1][1];
      u32x2 p0 = __builtin_amdgcn_permlane32_swap(wl0, wh0, false, false);
      u32x2 p1 = __builtin_amdgcn_permlane32_swap(wl1, wh1, false, false);
      union { unsigned int u[4]; bf16x8 v; } pb;
      pb.u[0] = p0[0];   // {wl_lo, wh_lo}
      pb.u[1] = p1[0];
      pb.u[2] = p0[1];   // {wl_hi, wh_hi}
      pb.u[3] = p1[1];
      __builtin_amdgcn_s_setprio(1);
      #pragma unroll
      for (int dt = 0; dt < 4; ++dt) {
        const int row = 32 * dt + l31;
        bf16x8 vf = *(const bf16x8*)(VT_ + row * 128 +
                                     (((2 * ks + (hi ? 1 : 0)) ^ (row & 7)) << 4));
        oacc[dt] = __builtin_amdgcn_mfma_f32_32x32x16_bf16(vf, pb.v, oacc[dt], 0, 0, 0);
      }
      __builtin_amdgcn_s_setprio(0);
    }

    __syncthreads();  // drains exactly the staging the next tile needs
  }
#undef STAGE

  // ---- epilogue: lane holds O^T[d = 32*dt + crow(reg,hi)][q = l31] ----
  const float sc = direct ? (1.f / lsum) : 1.f;
  float* dst = direct ? (out + qg * 128)
                      : (part + ((size_t)split * 16384 + qg) * 128);
  #pragma unroll
  for (int dt = 0; dt < 4; ++dt)
    #pragma unroll
    for (int rq = 0; rq < 4; ++rq) {
      f32x4 v = { oacc[dt][4 * rq + 0] * sc, oacc[dt][4 * rq + 1] * sc,
                  oacc[dt][4 * rq + 2] * sc, oacc[dt][4 * rq + 3] * sc };
      *(f32x4*)(dst + dt * 32 + rq * 8 + (hi ? 4 : 0)) = v;
    }
  if (!direct && lane < 32)
    ml[(size_t)split * 16384 + qg] = make_float2(m, lsum);
}

// merge: combine ns softmax partials. grid 2048 x 256, one float4 per thread.
__global__ __launch_bounds__(256) void merge_k(const float* __restrict__ part,
                                               const float2* __restrict__ ml,
                                               float* __restrict__ out, int ns) {
  const int idx = blockIdx.x * 256 + threadIdx.x;  // 0 .. 16384*32-1
  const int row = idx >> 5;
  const int c4  = idx & 31;

  float M = -__builtin_inff();
  for (int s = 0; s < ns; ++s) M = fmaxf(M, ml[s * 16384 + row].x);
  float L = 0.f;
  for (int s = 0; s < ns; ++s) {
    const float2 v = ml[s * 16384 + row];
    L += v.y * exp2f(v.x - M);
  }
  const float invL = 1.f / L;

  f32x4 o = (f32x4){0.f, 0.f, 0.f, 0.f};
  for (int s = 0; s < ns; ++s) {
    const float wgt = exp2f(ml[s * 16384 + row].x - M) * invL;
    const f32x4 a = *(const f32x4*)(part + ((size_t)s * 16384 + row) * 128 + c4 * 4);
    o += a * wgt;
  }
  *(f32x4*)(out + (size_t)row * 128 + c4 * 4) = o;
}

extern "C" void kernel_launch(void* const* d_in, const int* in_sizes, int n_in,
                              void* d_out, int out_size, void* d_ws, size_t ws_size,
                              hipStream_t stream) {
  (void)in_sizes; (void)n_in; (void)out_size;
  const float* x  = (const float*)d_in[0];
  const float* Wq = (const float*)d_in[1];
  const float* bq = (const float*)d_in[2];
  const float* Wk = (const float*)d_in[3];
  const float* bk = (const float*)d_in[4];
  const float* Wv = (const float*)d_in[5];
  const float* bv = (const float*)d_in[6];
  float* out = (float*)d_out;

  // workspace layout
  char* ws = (char*)d_ws;
  short* Wt = (short*)ws;                           // 786432 B  : Wt bf16 fragment-major
  short* Qb = (short*)(ws + 786432);                // 4 MiB     : Q bf16 [16384][128]
  short* Kb = (short*)(ws + 786432 + 4194304);      // 4 MiB     : K bf16 [16384][128]
  short* Vt = (short*)(ws + 786432 + 2 * 4194304);  // 4 MiB     : V^T bf16 [4][128][4096]
  const size_t base = 786432 + 3ull * 4194304;      // 13,369,344

  const size_t per_split = 16384ull * 128 * 4 + 16384ull * 8;
  int ns = 0;
  if (ws_size >= base + 4 * per_split)      ns = 4;
  else if (ws_size >= base + 2 * per_split) ns = 2;
  const int direct = (ns == 0);
  if (direct) ns = 1;

  float*  part = (float*)(ws + base);
  float2* mlp  = (float2*)(ws + base + (size_t)ns * 16384ull * 128 * 4);

  wprep_k<<<dim3(1536), dim3(256), 0, stream>>>(Wq, Wk, Wv, Wt);
  proj_k<<<dim3(256), dim3(512), 0, stream>>>(x, Wt, bq, bk, bv, Qb, Kb, Vt);
  attn_part_k<<<dim3(128 * ns), dim3(256), 0, stream>>>(Qb, Kb, Vt, part, mlp, out,
                                                        ns, direct);
  if (!direct)
    merge_k<<<dim3(2048), dim3(256), 0, stream>>>(part, mlp, out, ns);
}